// Round 13
// baseline (70.087 us; speedup 1.0000x reference)
//
#include <hip/hip_runtime.h>
#include <math.h>

#define T_LEN 1024
#define PRED_LEN 256
#define OUT_T (T_LEN + PRED_LEN)
#define DM 256
#define KSEL 32
#define RTAU 1e-4f

#define SPAD(i)  ((i) + ((i) >> 5))   // float arrays (twiddles)
#define PAD16(i) ((i) + ((i) >> 4))   // float2 arrays (spectra)

// W8[e] = exp(-2*pi*i*e/8)
#define R2F 0.70710678118654752440f
__device__ __constant__ float W8RF[8] = { 1.f,  R2F, 0.f, -R2F, -1.f, -R2F, 0.f,  R2F };
__device__ __constant__ float W8IF[8] = { 0.f, -R2F, -1.f, -R2F, 0.f,  R2F, 1.f,  R2F };

// ---------------- Kernel T: twiddle tables W[e] = exp(-2pi*i*e/1024), fp64 + fp32 ----------------
__global__ void fl_twiddle_kernel(double* __restrict__ gwr, double* __restrict__ gwi,
                                  float* __restrict__ gwrF, float* __restrict__ gwiF) {
    int e = blockIdx.x * 64 + threadIdx.x;
    double ang = (double)e * (6.283185307179586476925286766559 / 1024.0);
    double c = cos(ang), s = -sin(ang);
    gwr[e] = c; gwi[e] = s;
    gwrF[e] = (float)c; gwiF[e] = (float)s;
}

// ---- 512-pt FFT core (8 x 64 four-step). thread (w, lane): outputs X[k], k = (2w+q) + 8*rev6(lane)
__device__ __forceinline__ void fft512(const float2* __restrict__ zin,
                                       const float* __restrict__ twR,
                                       const float* __restrict__ twI,
                                       int lane, int w, float2* out2) {
    float2 zv[8];
#pragma unroll
    for (int n1 = 0; n1 < 8; ++n1) zv[n1] = zin[PAD16(lane + (n1 << 6))];
    float ar[2], ai[2];
#pragma unroll
    for (int q = 0; q < 2; ++q) {
        const int k1 = (w << 1) | q;
        float cr = 0.f, ci = 0.f;
#pragma unroll
        for (int n1 = 0; n1 < 8; ++n1) {
            int e = (k1 * n1) & 7;
            float wr = W8RF[e], wi = W8IF[e];
            cr += zv[n1].x * wr - zv[n1].y * wi;
            ci += zv[n1].x * wi + zv[n1].y * wr;
        }
        int et = (lane * k1) << 1;            // W512^(lane*k1) = W1024^(2*lane*k1) <= 882
        float twr = twR[SPAD(et)], twi = twI[SPAD(et)];
        ar[q] = cr * twr - ci * twi;
        ai[q] = cr * twi + ci * twr;
    }
#pragma unroll
    for (int s = 0; s < 6; ++s) {
        const int half = 32 >> s;
        const int e = (lane & (half - 1)) << s;
        const float wr = twR[SPAD(e << 4)];   // W64^e = W1024^(16e)
        const float wi = twI[SPAD(e << 4)];
        const bool up = (lane & half) != 0;
#pragma unroll
        for (int q = 0; q < 2; ++q) {
            float orr = __shfl_xor(ar[q], half);
            float oii = __shfl_xor(ai[q], half);
            float sr = ar[q] + orr, si = ai[q] + oii;
            float dr = orr - ar[q], di = oii - ai[q];
            ar[q] = up ? (dr * wr - di * wi) : sr;
            ai[q] = up ? (dr * wi + di * wr) : si;
        }
    }
    out2[0] = float2{ ar[0], ai[0] };
    out2[1] = float2{ ar[1], ai[1] };
}

// ---------------- Fused per-column kernel: rFFT + hist top-32 + fp64 refine + irFFT synthesis ----
// grid = 2048 blocks (one real column each), block = 256 threads = 4 waves; 8 blocks/CU.
__global__ void __launch_bounds__(256, 8)
fl_fused_kernel(const float* __restrict__ x,
                const double* __restrict__ gwr, const double* __restrict__ gwi,
                const float* __restrict__ gwrF, const float* __restrict__ gwiF,
                float* __restrict__ out) {
    __shared__ float twR[SPAD(1023) + 1], twI[SPAD(1023) + 1];   // fp32 twiddles (persist)
    __shared__ float2 regA[PAD16(511) + 1];   // z -> Z -> hist -> conj(G)
    __shared__ float2 spX[PAD16(511) + 1];    // X spectrum (k = 1..511)
    __shared__ unsigned selw[16];             // 512-bit selection set

    const int tid  = threadIdx.x;
    const int lane = tid & 63;
    const int w    = tid >> 6;

    const int bid = blockIdx.x;
    const int sp  = ((bid & 7) << 8) | (bid >> 3);   // XCD-chunked, bijective over 2048
    const int b   = sp >> 8;
    const int d   = sp & 255;

    // stage fp32 twiddles; load column as z[n] = x[2n] + i*x[2n+1]
    for (int j = 0; j < 4; ++j) {
        int e = tid + (j << 8);
        twR[SPAD(e)] = gwrF[e];
        twI[SPAD(e)] = gwiF[e];
    }
    {
        const float* xc = x + (((size_t)b << 10) << 8) + d;
        for (int j = 0; j < 2; ++j) {
            int n = tid + (j << 8);
            float xe = xc[(size_t)(2 * n) << 8];
            float xo = xc[(size_t)(2 * n + 1) << 8];
            regA[PAD16(n)] = float2{ xe, xo };
        }
    }
    if (tid < 16) selw[tid] = 0u;
    __syncthreads();

    // ---- FFT1: Z = FFT512(z)
    float2 zo[2];
    fft512(regA, twR, twI, lane, w, zo);
    const int krev = (int)(__brev((unsigned)lane) >> 26);
    __syncthreads();                 // all z reads done; regA becomes Z
#pragma unroll
    for (int q = 0; q < 2; ++q) {
        int k = ((w << 1) | q) + (krev << 3);
        regA[PAD16(k)] = zo[q];
    }
    __syncthreads();

    // ---- untangle: X[k] = E[k] + W^k*O[k], k = tid, tid+256
    for (int j = 0; j < 2; ++j) {
        int k = tid + (j << 8);
        int kk = (512 - k) & 511;
        float2 Zk = regA[PAD16(k)];
        float2 Zm = regA[PAD16(kk)];
        float Er = 0.5f * (Zk.x + Zm.x), Ei = 0.5f * (Zk.y - Zm.y);
        float Dr = 0.5f * (Zk.x - Zm.x), Di = 0.5f * (Zk.y + Zm.y);
        float Or = Di, Oi = -Dr;                       // O = -i*D
        float wr = twR[SPAD(k)], wi = twI[SPAD(k)];
        spX[PAD16(k)] = float2{ Er + (Or * wr - Oi * wi),
                                Ei + (Or * wi + Oi * wr) };
    }
    __syncthreads();

    // ---- histogram top-32 (wave 0) + fp64 boundary refinement; writes selw bits
    if (tid < 64) {
        int* histc = (int*)&regA[0];   // 256 ints; Z is dead

        float v[8]; int hiw[8];
#pragma unroll
        for (int q = 0; q < 8; ++q) {
            float2 X = spX[PAD16((q << 6) | lane)];
            v[q] = X.x * X.x + X.y * X.y;
        }
        if (lane == 0) v[0] = -1.0f;   // exclude m=0; m=512 excluded by range
#pragma unroll
        for (int q = 0; q < 8; ++q) hiw[q] = __float_as_int(v[q]);

        int mx = hiw[0];
#pragma unroll
        for (int q = 1; q < 8; ++q) mx = max(mx, hiw[q]);
#pragma unroll
        for (int off = 1; off < 64; off <<= 1) mx = max(mx, __shfl_xor(mx, off));

        const int base = (mx >> 20) - 250;
        int idx[8];
#pragma unroll
        for (int q = 0; q < 8; ++q) {
            int t = (hiw[q] >> 20) - base;
            idx[q] = t < 0 ? 0 : t;
        }

        *reinterpret_cast<int4*>(&histc[lane << 2]) = int4{0, 0, 0, 0};
#pragma unroll
        for (int q = 0; q < 8; ++q) atomicAdd(&histc[idx[q]], 1);

        int4 cc = *reinterpret_cast<int4*>(&histc[lane << 2]);
        int s_local = cc.x + cc.y + cc.z + cc.w;

        int s = s_local;
#pragma unroll
        for (int off = 1; off < 64; off <<= 1) {
            int t = __shfl_down(s, off);
            if (lane + off < 64) s += t;
        }
        const int S_gt = s - s_local;
        const int A3 = S_gt;
        const int A2 = A3 + cc.w;
        const int A1 = A2 + cc.z;
        const int A0 = A1 + cc.y;

        int foundB = -1, foundR = 0;
        if (A0 < KSEL && A0 + cc.x >= KSEL) { foundB = (lane << 2) | 0; foundR = KSEL - A0; }
        if (A1 < KSEL && A1 + cc.y >= KSEL) { foundB = (lane << 2) | 1; foundR = KSEL - A1; }
        if (A2 < KSEL && A2 + cc.z >= KSEL) { foundB = (lane << 2) | 2; foundR = KSEL - A2; }
        if (A3 < KSEL && A3 + cc.w >= KSEL) { foundB = (lane << 2) | 3; foundR = KSEL - A3; }

        unsigned long long fm = __ballot(foundB >= 0);
        const int srcB = (int)(__ffsll((unsigned long long)fm) - 1);
        const int B = __shfl(foundB, srcB);
        const int r = __shfl(foundR, srcB);

        unsigned selmask = 0, candmask = 0;
#pragma unroll
        for (int q = 0; q < 8; ++q) {
            if (idx[q] > B) selmask |= (1u << q);
            else if (idx[q] == B) candmask |= (1u << q);
        }

        for (int it = 0; it < r; ++it) {
            float bv = -2.0f; int bq = -1;
#pragma unroll
            for (int q = 0; q < 8; ++q) {
                bool cand = ((candmask >> q) & 1u) != 0;
                if (cand && v[q] > bv) { bv = v[q]; bq = q; }
            }
            int bi = (bq < 0) ? 0x7FFFFFFF : ((bq << 6) | lane);
#pragma unroll
            for (int off = 1; off < 64; off <<= 1) {
                float ov = __shfl_xor(bv, off);
                int   oi = __shfl_xor(bi, off);
                if (ov > bv || (ov == bv && oi < bi)) { bv = ov; bi = oi; }
            }
            if (bi != 0x7FFFFFFF && lane == (bi & 63)) {
                unsigned bit = 1u << (bi >> 6);
                selmask  |= bit;
                candmask &= ~bit;
            }
        }

        // fp64 refinement when fp32 rank-32/33 gap too small (reads x from global)
        {
            float vminS = 3.0e38f, vmaxU = -3.0e38f;
#pragma unroll
            for (int q = 0; q < 8; ++q) {
                if ((selmask >> q) & 1u) vminS = fminf(vminS, v[q]);
                else                     vmaxU = fmaxf(vmaxU, v[q]);
            }
#pragma unroll
            for (int off = 1; off < 64; off <<= 1) {
                vminS = fminf(vminS, __shfl_xor(vminS, off));
                vmaxU = fmaxf(vmaxU, __shfl_xor(vmaxU, off));
            }
            const float tau = RTAU * vminS;
            if (vminS - vmaxU < tau) {
                const float lo = vmaxU - tau, hi = vminS + tau;
                unsigned candq = 0; int nAbove = 0;
#pragma unroll
                for (int q = 0; q < 8; ++q) {
                    bool inw = (v[q] >= lo) && (v[q] <= hi);
                    if (inw) candq |= (1u << q);
                    if (((selmask >> q) & 1u) && v[q] > hi) ++nAbove;
                }
#pragma unroll
                for (int off = 1; off < 64; off <<= 1) nAbove += __shfl_xor(nAbove, off);
                const int kneed = KSEL - nAbove;
                selmask &= ~candq;

                const float* xcol = x + (((size_t)b << 10) << 8) + d;
                double sV = -1.0; int sSrc = 0; int cnum = 0;
                for (int q = 0; q < 8; ++q) {
                    unsigned long long bal = __ballot((candq >> q) & 1u);
                    while (bal) {
                        int srcl = (int)(__ffsll(bal) - 1);
                        bal &= bal - 1;
                        int m = (q << 6) | srcl;
                        double sr = 0.0, si = 0.0;
                        for (int u = 0; u < 16; ++u) {
                            int n = lane + (u << 6);
                            double xvd = (double)xcol[(size_t)n << 8];
                            int e = (m * n) & 1023;
                            sr = fma(xvd, gwr[e], sr);
                            si = fma(xvd, gwi[e], si);
                        }
#pragma unroll
                        for (int off = 1; off < 64; off <<= 1) {
                            sr += __shfl_xor(sr, off);
                            si += __shfl_xor(si, off);
                        }
                        if (lane == cnum) { sV = sr * sr + si * si; sSrc = (q << 6) | srcl; }
                        ++cnum;
                        if (cnum >= 64) break;
                    }
                    if (cnum >= 64) break;
                }
                for (int it = 0; it < kneed; ++it) {
                    double bv = sV; int bl = lane;
#pragma unroll
                    for (int off = 1; off < 64; off <<= 1) {
                        double ov = __shfl_xor(bv, off);
                        int    ol = __shfl_xor(bl, off);
                        if (ov > bv || (ov == bv && ol < bl)) { bv = ov; bl = ol; }
                    }
                    int wsrc = __shfl(sSrc, bl);
                    if (lane == (wsrc & 63)) selmask |= 1u << (wsrc >> 6);
                    if (lane == bl) sV = -2.0;
                }
            }
        }

#pragma unroll
        for (int q = 0; q < 8; ++q) {
            if ((selmask >> q) & 1u) {
                int m = (q << 6) | lane;
                atomicOr(&selw[m >> 5], 1u << (m & 31));
            }
        }
    }
    __syncthreads();

    // ---- build conj(G), G[k] = E'[k] + i*O'[k] of masked Y; into regA (hist dead)
    for (int j = 0; j < 2; ++j) {
        int k = tid + (j << 8);
        float2 g{ 0.f, 0.f };
        if (k != 0) {
            int kk = 512 - k;       // 1..511
            bool sk  = (selw[k  >> 5] >> (k  & 31)) & 1u;
            bool skk = (selw[kk >> 5] >> (kk & 31)) & 1u;
            float2 Yk = spX[PAD16(k)];  if (!sk)  Yk = float2{ 0.f, 0.f };
            float2 Ym = spX[PAD16(kk)]; if (!skk) Ym = float2{ 0.f, 0.f };
            float Epr = 0.5f * (Yk.x + Ym.x), Epi = 0.5f * (Yk.y - Ym.y);
            float Dpr = 0.5f * (Yk.x - Ym.x), Dpi = 0.5f * (Yk.y + Ym.y);
            float wr = twR[SPAD(k)], wi = -twI[SPAD(k)];    // conj(W^k)
            float Opr = Dpr * wr - Dpi * wi;
            float Opi = Dpr * wi + Dpi * wr;
            g = float2{ Epr - Opi, -(Epi + Opr) };          // conj(E' + i O')
        }
        regA[PAD16(k)] = g;
    }
    __syncthreads();

    // ---- FFT2: C = FFT512(conj(G)); y[2n] = C.r/512, y[2n+1] = -C.i/512
    float2 co[2];
    fft512(regA, twR, twI, lane, w, co);
    {
        const float S = 1.0f / 512.0f;
        float* ob = out + ((size_t)b * OUT_T) * DM + d;
#pragma unroll
        for (int q = 0; q < 2; ++q) {
            int n = ((w << 1) | q) + (krev << 3);
            float y0 = co[q].x * S;
            float y1 = -co[q].y * S;
            ob[(size_t)(2 * n)     << 8] = y0;
            ob[(size_t)(2 * n + 1) << 8] = y1;
            if (n < 128) {   // period-1024 tail duplication
                ob[(size_t)(2 * n + T_LEN)     << 8] = y0;
                ob[(size_t)(2 * n + 1 + T_LEN) << 8] = y1;
            }
        }
    }
}

extern "C" void kernel_launch(void* const* d_in, const int* in_sizes, int n_in,
                              void* d_out, int out_size, void* d_ws, size_t ws_size,
                              hipStream_t stream) {
    const float* x = (const float*)d_in[0];
    float* out = (float*)d_out;

    char* w = (char*)d_ws;
    double* gwr  = (double*)(w);
    double* gwi  = (double*)(w + 1024 * sizeof(double));
    float*  gwrF = (float*)(w + 2048 * sizeof(double));
    float*  gwiF = (float*)(w + 2048 * sizeof(double) + 1024 * sizeof(float));

    hipLaunchKernelGGL(fl_twiddle_kernel, dim3(16), dim3(64), 0, stream, gwr, gwi, gwrF, gwiF);
    hipLaunchKernelGGL(fl_fused_kernel, dim3(2048), dim3(256), 0, stream,
                       x, gwr, gwi, gwrF, gwiF, out);
}

// Round 14
// 43.310 us; speedup vs baseline: 1.6183x; 1.6183x over previous
//
#include <hip/hip_runtime.h>
#include <math.h>

#define T_LEN 1024
#define PRED_LEN 256
#define OUT_T (T_LEN + PRED_LEN)
#define DM 256
#define KSEL 32
#define RTAU 1e-4f

#define PAD16(i) ((i) + ((i) >> 4))   // float2 arrays
#define C1024 0.006135923151542565f   // 2*pi/1024

// W16[e] = exp(-2*pi*i*e/16), fp32
__device__ __constant__ float W16RF[16] = {
    1.0f,  0.92387953f,  0.70710678f,  0.38268343f, 0.0f, -0.38268343f, -0.70710678f, -0.92387953f,
   -1.0f, -0.92387953f, -0.70710678f, -0.38268343f, 0.0f,  0.38268343f,  0.70710678f,  0.92387953f };
__device__ __constant__ float W16IF[16] = {
    0.0f, -0.38268343f, -0.70710678f, -0.92387953f, -1.0f, -0.92387953f, -0.70710678f, -0.38268343f,
    0.0f,  0.38268343f,  0.70710678f,  0.92387953f,  1.0f,  0.92387953f,  0.70710678f,  0.38268343f };

// ---------------- Kernel T: fp64 twiddle table (refinement only) ----------------
__global__ void fl_twiddle_kernel(double* __restrict__ gwr, double* __restrict__ gwi) {
    int e = blockIdx.x * 64 + threadIdx.x;
    double ang = (double)e * (6.283185307179586476925286766559 / 1024.0);
    gwr[e] = cos(ang);
    gwi[e] = -sin(ang);
}

// ---- 1024-pt packed FFT core (16x64 four-step), twiddles via native sincos ----
// thread (w, lane): outputs X[k], k = ((w<<2)|q) + 16*rev6(lane)
__device__ __forceinline__ void fft1024(const float2* __restrict__ xin,
                                        int lane, int w, float* ar, float* ai) {
    float Fr[4][4], Fi[4][4];
#pragma unroll
    for (int n1a = 0; n1a < 4; ++n1a) {
        float2 a  = xin[lane + 64 * (n1a + 0)];
        float2 bb = xin[lane + 64 * (n1a + 4)];
        float2 cV = xin[lane + 64 * (n1a + 8)];
        float2 d  = xin[lane + 64 * (n1a + 12)];
        float t0r = a.x + cV.x, t0i = a.y + cV.y;
        float t1r = a.x - cV.x, t1i = a.y - cV.y;
        float t2r = bb.x + d.x, t2i = bb.y + d.y;
        float t3r = bb.x - d.x, t3i = bb.y - d.y;
        Fr[n1a][0] = t0r + t2r;  Fi[n1a][0] = t0i + t2i;
        Fr[n1a][2] = t0r - t2r;  Fi[n1a][2] = t0i - t2i;
        Fr[n1a][1] = t1r + t3i;  Fi[n1a][1] = t1i - t3r;   // t1 - i*t3
        Fr[n1a][3] = t1r - t3i;  Fi[n1a][3] = t1i + t3r;   // t1 + i*t3
    }
#pragma unroll
    for (int q = 0; q < 4; ++q) {
        const int k1 = (w << 2) | q;
        float cr = Fr[0][q], ci = Fi[0][q];
#pragma unroll
        for (int n1a = 1; n1a < 4; ++n1a) {
            int e = (n1a * k1) & 15;
            float wr = W16RF[e], wi = W16IF[e];
            cr += Fr[n1a][q] * wr - Fi[n1a][q] * wi;
            ci += Fr[n1a][q] * wi + Fi[n1a][q] * wr;
        }
        // twiddle W1024^(lane*k1), lane*k1 <= 945
        float th = (float)(lane * k1) * C1024;
        float sn, cs; __sincosf(th, &sn, &cs);
        ar[q] = cr * cs + ci * sn;          // (cr + i ci)*(cs - i sn)
        ai[q] = ci * cs - cr * sn;
    }
#pragma unroll
    for (int s = 0; s < 6; ++s) {
        const int half = 32 >> s;
        const int e = (lane & (half - 1)) << s;          // < 32
        float th = (float)(e << 4) * C1024;              // W64^e = W1024^(16e)
        float sn, cs; __sincosf(th, &sn, &cs);
        const bool up = (lane & half) != 0;
#pragma unroll
        for (int q = 0; q < 4; ++q) {
            float orr = __shfl_xor(ar[q], half);
            float oii = __shfl_xor(ai[q], half);
            float sr = ar[q] + orr, si = ai[q] + oii;
            float dr = orr - ar[q], di = oii - ai[q];
            ar[q] = up ? (dr * cs + di * sn) : sr;
            ai[q] = up ? (di * cs - dr * sn) : si;
        }
    }
}

// ---------------- Fused: fp32 FFT + hist top-32 (bitset) + fp64 refine + inverse-FFT synthesis ----------------
// grid = 1024 blocks (one column-pair each), block = 256 threads = 4 waves; ~17.1 KB LDS -> 8 blocks/CU.
__global__ void __launch_bounds__(256, 4)
fl_fused_kernel(const float* __restrict__ x,
                const double* __restrict__ gwr, const double* __restrict__ gwi,
                float* __restrict__ out) {
    __shared__ float2 spP[PAD16(1023) + 1];   // packed spectrum (padded float2)
    __shared__ char smemU[8192];              // union: xsh (FFT1 in) | {mg, hist} | Zc (FFT2 in)
    __shared__ unsigned selw[64];             // selection bitsets: [c][k>>5]
    float2* xsh  = (float2*)smemU;
    float*  mg   = (float*)smemU;             // [1024]
    int*    hist = (int*)(smemU + 4096);      // [512]

    const int tid  = threadIdx.x;
    const int lane = tid & 63;
    const int w    = tid >> 6;

    const int bid = blockIdx.x;
    const int sp  = ((bid & 7) << 7) | (bid >> 3);   // XCD-chunked, bijective over 1024
    const int b   = sp >> 7;
    const int d0  = (sp & 127) << 1;

    // load the packed column-pair into LDS
    for (int j = 0; j < 4; ++j) {
        int e = tid + (j << 8);
        xsh[e] = *reinterpret_cast<const float2*>(&x[(((size_t)(b << 10) + e) << 8) + d0]);
    }
    if (tid < 64) selw[tid] = 0u;
    __syncthreads();

    // ---- FFT 1: forward transform of packed pair
    float ar[4], ai[4];
    fft1024(xsh, lane, w, ar, ai);

    const int krev = (int)(__brev((unsigned)lane) >> 26);  // rev6(lane)
    __syncthreads();                                       // xsh reads done (mg reuse next)
#pragma unroll
    for (int q = 0; q < 4; ++q) {
        int k = ((w << 2) | q) + (krev << 4);
        spP[PAD16(k)] = float2{ ar[q], ai[q] };
    }
    __syncthreads();

    // ---- magnitudes for both packed columns (conjugate-symmetry unpack); overwrites xsh
#pragma unroll
    for (int h = 0; h < 2; ++h) {
        int m = tid + (h << 8);
        int n = (1024 - m) & 1023;
        float2 Pk = spP[PAD16(m)];
        float2 Pn = spP[PAD16(n)];
        float rr0 = 0.5f * (Pk.x + Pn.x), ii0 = 0.5f * (Pk.y - Pn.y);
        float rr1 = 0.5f * (Pk.y + Pn.y), ii1 = 0.5f * (Pn.x - Pk.x);
        mg[m]       = rr0 * rr0 + ii0 * ii0;
        mg[512 + m] = rr1 * rr1 + ii1 * ii1;
    }
    __syncthreads();

    // ---- histogram top-32 (waves 0,1: one wave per column) + fp64 boundary refinement
    if (tid < 128) {
        const int c = tid >> 6;
        const float* mgc = mg + (c << 9);
        int* histc = hist + (c << 8);

        float v[8]; int hiw[8];
#pragma unroll
        for (int q = 0; q < 8; ++q) v[q] = mgc[(q << 6) | lane];
        if (lane == 0) v[0] = -1.0f;   // exclude m=0; m=512 excluded by range
#pragma unroll
        for (int q = 0; q < 8; ++q) hiw[q] = __float_as_int(v[q]);

        int mx = hiw[0];
#pragma unroll
        for (int q = 1; q < 8; ++q) mx = max(mx, hiw[q]);
#pragma unroll
        for (int off = 1; off < 64; off <<= 1) mx = max(mx, __shfl_xor(mx, off));

        const int base = (mx >> 20) - 250;
        int idx[8];
#pragma unroll
        for (int q = 0; q < 8; ++q) {
            int t = (hiw[q] >> 20) - base;
            idx[q] = t < 0 ? 0 : t;
        }

        *reinterpret_cast<int4*>(&histc[lane << 2]) = int4{0, 0, 0, 0};
#pragma unroll
        for (int q = 0; q < 8; ++q) atomicAdd(&histc[idx[q]], 1);

        int4 cc = *reinterpret_cast<int4*>(&histc[lane << 2]);
        int s_local = cc.x + cc.y + cc.z + cc.w;

        int s = s_local;
#pragma unroll
        for (int off = 1; off < 64; off <<= 1) {
            int t = __shfl_down(s, off);
            if (lane + off < 64) s += t;
        }
        const int S_gt = s - s_local;
        const int A3 = S_gt;
        const int A2 = A3 + cc.w;
        const int A1 = A2 + cc.z;
        const int A0 = A1 + cc.y;

        int foundB = -1, foundR = 0;
        if (A0 < KSEL && A0 + cc.x >= KSEL) { foundB = (lane << 2) | 0; foundR = KSEL - A0; }
        if (A1 < KSEL && A1 + cc.y >= KSEL) { foundB = (lane << 2) | 1; foundR = KSEL - A1; }
        if (A2 < KSEL && A2 + cc.z >= KSEL) { foundB = (lane << 2) | 2; foundR = KSEL - A2; }
        if (A3 < KSEL && A3 + cc.w >= KSEL) { foundB = (lane << 2) | 3; foundR = KSEL - A3; }

        unsigned long long fm = __ballot(foundB >= 0);
        const int srcB = (int)(__ffsll((unsigned long long)fm) - 1);
        const int B = __shfl(foundB, srcB);
        const int r = __shfl(foundR, srcB);

        unsigned selmask = 0, candmask = 0;
#pragma unroll
        for (int q = 0; q < 8; ++q) {
            if (idx[q] > B) selmask |= (1u << q);
            else if (idx[q] == B) candmask |= (1u << q);
        }

        for (int it = 0; it < r; ++it) {
            float bv = -2.0f; int bq = -1;
#pragma unroll
            for (int q = 0; q < 8; ++q) {
                bool cand = ((candmask >> q) & 1u) != 0;
                if (cand && v[q] > bv) { bv = v[q]; bq = q; }
            }
            int bi = (bq < 0) ? 0x7FFFFFFF : ((bq << 6) | lane);
#pragma unroll
            for (int off = 1; off < 64; off <<= 1) {
                float ov = __shfl_xor(bv, off);
                int   oi = __shfl_xor(bi, off);
                if (ov > bv || (ov == bv && oi < bi)) { bv = ov; bi = oi; }
            }
            if (bi != 0x7FFFFFFF && lane == (bi & 63)) {
                unsigned bit = 1u << (bi >> 6);
                selmask  |= bit;
                candmask &= ~bit;
            }
        }

        // ---- fp64 refinement when the rank-32/33 fp32 gap is too small (reads x from global)
        {
            float vminS = 3.0e38f, vmaxU = -3.0e38f;
#pragma unroll
            for (int q = 0; q < 8; ++q) {
                if ((selmask >> q) & 1u) vminS = fminf(vminS, v[q]);
                else                     vmaxU = fmaxf(vmaxU, v[q]);
            }
#pragma unroll
            for (int off = 1; off < 64; off <<= 1) {
                vminS = fminf(vminS, __shfl_xor(vminS, off));
                vmaxU = fmaxf(vmaxU, __shfl_xor(vmaxU, off));
            }
            const float tau = RTAU * vminS;
            if (vminS - vmaxU < tau) {            // wave-uniform, rare
                const float lo = vmaxU - tau, hi = vminS + tau;
                unsigned candq = 0; int nAbove = 0;
#pragma unroll
                for (int q = 0; q < 8; ++q) {
                    bool inw = (v[q] >= lo) && (v[q] <= hi);
                    if (inw) candq |= (1u << q);
                    if (((selmask >> q) & 1u) && v[q] > hi) ++nAbove;
                }
#pragma unroll
                for (int off = 1; off < 64; off <<= 1) nAbove += __shfl_xor(nAbove, off);
                const int kneed = KSEL - nAbove;
                selmask &= ~candq;                 // drop window members; re-pick in fp64

                const float* xcol = x + ((size_t)(b << 10) << 8) + d0 + c;
                double sV = -1.0; int sSrc = 0; int cnum = 0;
                for (int q = 0; q < 8; ++q) {
                    unsigned long long bal = __ballot((candq >> q) & 1u);
                    while (bal) {
                        int srcl = (int)(__ffsll(bal) - 1);
                        bal &= bal - 1;
                        int m = (q << 6) | srcl;
                        double sr = 0.0, si = 0.0;
                        for (int u = 0; u < 16; ++u) {
                            int n = lane + (u << 6);
                            double xvd = (double)xcol[(size_t)n << 8];
                            int e = (m * n) & 1023;
                            sr = fma(xvd, gwr[e], sr);
                            si = fma(xvd, gwi[e], si);
                        }
#pragma unroll
                        for (int off = 1; off < 64; off <<= 1) {
                            sr += __shfl_xor(sr, off);
                            si += __shfl_xor(si, off);
                        }
                        if (lane == cnum) { sV = sr * sr + si * si; sSrc = (q << 6) | srcl; }
                        ++cnum;
                        if (cnum >= 64) break;
                    }
                    if (cnum >= 64) break;
                }
                for (int it = 0; it < kneed; ++it) {
                    double bv = sV; int bl = lane;
#pragma unroll
                    for (int off = 1; off < 64; off <<= 1) {
                        double ov = __shfl_xor(bv, off);
                        int    ol = __shfl_xor(bl, off);
                        if (ov > bv || (ov == bv && ol < bl)) { bv = ov; bl = ol; }
                    }
                    int wsrc = __shfl(sSrc, bl);
                    if (lane == (wsrc & 63)) selmask |= 1u << (wsrc >> 6);
                    if (lane == bl) sV = -2.0;
                }
            }
        }

        // ---- write selection bits (m and its conjugate mirror 1024-m)
#pragma unroll
        for (int q = 0; q < 8; ++q) {
            if ((selmask >> q) & 1u) {
                int m  = (q << 6) | lane;          // 1..511
                int mm = 1024 - m;                 // 513..1023
                atomicOr(&selw[(c << 5) | (m  >> 5)], 1u << (m  & 31));
                atomicOr(&selw[(c << 5) | (mm >> 5)], 1u << (mm & 31));
            }
        }
    }
    __syncthreads();

    // ---- build conj(Z) into smemU: Z[k] = s0*X0[k] + i*s1*X1[k]; Zc = (Z.r, -Z.i)
    {
        float2* zc = (float2*)smemU;
#pragma unroll
        for (int jj = 0; jj < 4; ++jj) {
            int k = tid + (jj << 8);
            int n = (1024 - k) & 1023;
            float2 Pk = spP[PAD16(k)];
            float2 Pn = spP[PAD16(n)];
            float X0r = 0.5f * (Pk.x + Pn.x), X0i = 0.5f * (Pk.y - Pn.y);
            float X1r = 0.5f * (Pk.y + Pn.y), X1i = 0.5f * (Pn.x - Pk.x);
            bool s0 = (selw[(k >> 5)]      >> (k & 31)) & 1u;
            bool s1 = (selw[32 + (k >> 5)] >> (k & 31)) & 1u;
            float Zr = (s0 ? X0r : 0.0f) - (s1 ? X1i : 0.0f);
            float Zi = (s0 ? X0i : 0.0f) + (s1 ? X1r : 0.0f);
            zc[k] = float2{ Zr, -Zi };
        }
    }
    __syncthreads();

    // ---- FFT 2 (inverse via conjugation): R[t] = DFT(conj(Z))[t] = conj(1024*y[t])
    fft1024(xsh, lane, w, ar, ai);

    // ---- write y: out0 = Re(R)/1024, out1 = -Im(R)/1024; duplicate t<256 to t+1024
    {
        const float S = 1.0f / 1024.0f;
        float2* o2 = reinterpret_cast<float2*>(out + (size_t)b * OUT_T * DM + d0);
#pragma unroll
        for (int q = 0; q < 4; ++q) {
            int t = ((w << 2) | q) + (krev << 4);
            float2 o{ ar[q] * S, -ai[q] * S };
            o2[(size_t)t * 128] = o;
            if (t < PRED_LEN) o2[(size_t)(t + T_LEN) * 128] = o;
        }
    }
}

extern "C" void kernel_launch(void* const* d_in, const int* in_sizes, int n_in,
                              void* d_out, int out_size, void* d_ws, size_t ws_size,
                              hipStream_t stream) {
    const float* x = (const float*)d_in[0];
    float* out = (float*)d_out;

    char* w = (char*)d_ws;
    double* gwr = (double*)(w);
    double* gwi = (double*)(w + 1024 * sizeof(double));

    hipLaunchKernelGGL(fl_twiddle_kernel, dim3(16), dim3(64), 0, stream, gwr, gwi);
    hipLaunchKernelGGL(fl_fused_kernel, dim3(1024), dim3(256), 0, stream,
                       x, gwr, gwi, out);
}